// Round 1
// baseline (592.958 us; speedup 1.0000x reference)
//
#include <hip/hip_runtime.h>
#include <math.h>

#define HID 64
#define BN_EPS 1e-5f

// ---------------- degree / CSR construction ----------------

__global__ __launch_bounds__(256) void k_count(const int* __restrict__ ei, int E,
                                               int* __restrict__ deg, int* __restrict__ cnt) {
    int e = blockIdx.x * 256 + threadIdx.x;
    if (e >= E) return;
    atomicAdd(&deg[ei[e]], 1);       // outdeg over src (reference: deg over row)
    atomicAdd(&cnt[ei[E + e]], 1);   // incoming count over dst (for CSR)
}

__global__ __launch_bounds__(256) void k_dis(const int* __restrict__ deg, float* __restrict__ dis, int n) {
    int v = blockIdx.x * 256 + threadIdx.x;
    if (v < n) dis[v] = rsqrtf((float)(deg[v] + 1));   // +1 self loop; deg>=1 always
}

// single-block exclusive scan over n ints (n ~ 50000): wave shuffles + cross-wave
__global__ __launch_bounds__(1024) void k_scan(const int* __restrict__ cnt, int* __restrict__ rowptr, int n) {
    __shared__ int wsum[16];
    __shared__ int carry_s;
    int tid = threadIdx.x, lane = tid & 63, wid = tid >> 6;
    if (tid == 0) carry_s = 0;
    __syncthreads();
    for (int base = 0; base < n; base += 1024) {
        int v = (base + tid < n) ? cnt[base + tid] : 0;
        int s = v;
        #pragma unroll
        for (int off = 1; off < 64; off <<= 1) {
            int t = __shfl_up(s, off, 64);
            if (lane >= off) s += t;
        }
        if (lane == 63) wsum[wid] = s;
        __syncthreads();
        if (wid == 0 && lane < 16) {
            int w = wsum[lane];
            #pragma unroll
            for (int off = 1; off < 16; off <<= 1) {
                int t = __shfl_up(w, off, 64);
                if (lane >= off) w += t;
            }
            wsum[lane] = w;  // inclusive scan of wave sums
        }
        __syncthreads();
        int waveoff = (wid == 0) ? 0 : wsum[wid - 1];
        int c = carry_s;
        if (base + tid < n) rowptr[base + tid] = c + (s + waveoff) - v;  // exclusive
        __syncthreads();
        if (tid == 1023) carry_s = c + wsum[15];
        __syncthreads();
    }
    if (threadIdx.x == 0) rowptr[n] = carry_s;
}

__global__ __launch_bounds__(256) void k_fill(const int* __restrict__ ei, int E,
                                              const int* __restrict__ rowptr,
                                              int* __restrict__ fill, int* __restrict__ eidx) {
    int e = blockIdx.x * 256 + threadIdx.x;
    if (e >= E) return;
    int dst = ei[E + e];
    int pos = rowptr[dst] + atomicAdd(&fill[dst], 1);
    eidx[pos] = ei[e];  // store src node id
}

// ---------------- BN stats (per-feature sum / sumsq over rows) ----------------

template <int F>
__global__ __launch_bounds__(256) void k_stats(const float* __restrict__ X, int n,
                                               float* __restrict__ stats) {
    const int RPB = 256 / F;                // sub-rows per block iteration
    int f = threadIdx.x & (F - 1);
    int rsub = threadIdx.x / F;
    float s = 0.f, q = 0.f;
    for (int r = blockIdx.x * RPB + rsub; r < n; r += gridDim.x * RPB) {
        float v = X[(size_t)r * F + f];     // coalesced: consecutive tid -> consecutive addr
        s += v; q += v * v;
    }
    __shared__ float shs[256], shq[256];
    shs[threadIdx.x] = s; shq[threadIdx.x] = q;
    __syncthreads();
    if (threadIdx.x < F) {
        #pragma unroll
        for (int k = 1; k < RPB; k++) { s += shs[threadIdx.x + k * F]; q += shq[threadIdx.x + k * F]; }
        atomicAdd(&stats[f], s);
        atomicAdd(&stats[F + f], q);
    }
}

// ---------------- fold BN into linear weights ----------------
// BN(x)@W = x@(a.*W) + (beta - mu.*a)@W ;  a = gamma*rsqrt(var+eps)

template <int K>
__global__ void k_fold(const float* __restrict__ stats, const float* __restrict__ gamma,
                       const float* __restrict__ beta, const float* __restrict__ W,
                       const float* __restrict__ bias, float n_inv,
                       float* __restrict__ Wout, float* __restrict__ bout, int has_bias) {
    int o = blockIdx.x;      // output column 0..63
    int f = threadIdx.x;     // input feature 0..K-1
    float mu = stats[f] * n_inv;
    float var = stats[K + f] * n_inv - mu * mu;
    float a = gamma[f] * rsqrtf(var + BN_EPS);
    float w = W[(size_t)f * HID + o];
    Wout[(size_t)f * HID + o] = a * w;
    float contrib = (beta[f] - mu * a) * w;
    __shared__ float sh[K];
    sh[f] = contrib;
    __syncthreads();
    #pragma unroll
    for (int off = K / 2; off > 0; off >>= 1) {
        if (f < off) sh[f] += sh[f + off];
        __syncthreads();
    }
    if (f == 0) bout[o] = sh[0] + (has_bias ? bias[o] : 0.f);
}

// ---------------- GEMM: out[n,64] = X[n,K] @ W[K,64] + b ; optional relu / dis-scale ----

template <int K, bool RELU, bool DIS>
__global__ __launch_bounds__(256) void k_gemm(const float* __restrict__ X, const float* __restrict__ W,
                                              const float* __restrict__ bias, const float* __restrict__ dis,
                                              float* __restrict__ out, int n) {
    int row = blockIdx.x * 256 + threadIdx.x;
    if (row >= n) return;
    float4 acc[16];
    const float4* b4 = (const float4*)bias;
    #pragma unroll
    for (int c = 0; c < 16; c++) acc[c] = b4[c];
    const float* xrow = X + (size_t)row * K;
    #pragma unroll 1
    for (int kc = 0; kc < K; kc += 32) {
        float4 xr[8];
        const float4* xp = (const float4*)(xrow + kc);
        #pragma unroll
        for (int i = 0; i < 8; i++) xr[i] = xp[i];
        #pragma unroll
        for (int kk = 0; kk < 32; kk++) {
            float xv = ((const float*)xr)[kk];
            const float4* w4 = (const float4*)(W + (size_t)(kc + kk) * HID);  // wave-uniform addr
            #pragma unroll
            for (int c = 0; c < 16; c++) {
                float4 w = w4[c];
                acc[c].x = fmaf(xv, w.x, acc[c].x);
                acc[c].y = fmaf(xv, w.y, acc[c].y);
                acc[c].z = fmaf(xv, w.z, acc[c].z);
                acc[c].w = fmaf(xv, w.w, acc[c].w);
            }
        }
    }
    float d = DIS ? dis[row] : 1.f;
    float4* o4 = (float4*)(out + (size_t)row * HID);
    #pragma unroll
    for (int c = 0; c < 16; c++) {
        float4 v = acc[c];
        v.x *= d; v.y *= d; v.z *= d; v.w *= d;
        if (RELU) { v.x = fmaxf(v.x, 0.f); v.y = fmaxf(v.y, 0.f); v.z = fmaxf(v.z, 0.f); v.w = fmaxf(v.w, 0.f); }
        o4[c] = v;
    }
}

// ---------------- aggregation: out_i = relu(dis_i*(s_i + sum_{j->i} s_j) + b) ----------------
// one wave per node, lane = feature

__global__ __launch_bounds__(256) void k_agg(const float* __restrict__ s, const int* __restrict__ rowptr,
                                             const int* __restrict__ eidx, const float* __restrict__ dis,
                                             const float* __restrict__ bias, float* __restrict__ out, int n) {
    int i = blockIdx.x * 4 + (threadIdx.x >> 6);
    if (i >= n) return;
    int lane = threadIdx.x & 63;
    float a0 = s[(size_t)i * HID + lane];   // self-loop term
    float a1 = 0.f, a2 = 0.f, a3 = 0.f;
    int p0 = rowptr[i], p1 = rowptr[i + 1];
    int p = p0;
    for (; p + 4 <= p1; p += 4) {
        int j0 = eidx[p], j1 = eidx[p + 1], j2 = eidx[p + 2], j3 = eidx[p + 3];
        a0 += s[(size_t)j0 * HID + lane];
        a1 += s[(size_t)j1 * HID + lane];
        a2 += s[(size_t)j2 * HID + lane];
        a3 += s[(size_t)j3 * HID + lane];
    }
    for (; p < p1; ++p) a0 += s[(size_t)eidx[p] * HID + lane];
    float v = dis[i] * ((a0 + a1) + (a2 + a3)) + bias[lane];
    out[(size_t)i * HID + lane] = fmaxf(v, 0.f);
}

// ---------------- global_add_pool over sorted batch ----------------

__global__ __launch_bounds__(256) void k_pool(const float* __restrict__ h, const int* __restrict__ batch,
                                              int n, float* __restrict__ out) {
    int g = blockIdx.x;
    // lower_bound(batch, g) and lower_bound(batch, g+1) — uniform across block
    int lo = 0, hi = n;
    while (lo < hi) { int mid = (lo + hi) >> 1; if (batch[mid] < g) lo = mid + 1; else hi = mid; }
    int start = lo;
    hi = n;
    while (lo < hi) { int mid = (lo + hi) >> 1; if (batch[mid] < g + 1) lo = mid + 1; else hi = mid; }
    int end = lo;
    int lane = threadIdx.x & 63;
    int rs = threadIdx.x >> 6;
    float acc = 0.f;
    for (int r = start + rs; r < end; r += 4) acc += h[(size_t)r * HID + lane];
    __shared__ float sh[256];
    sh[threadIdx.x] = acc;
    __syncthreads();
    if (threadIdx.x < 64) {
        acc = sh[threadIdx.x] + sh[64 + threadIdx.x] + sh[128 + threadIdx.x] + sh[192 + threadIdx.x];
        out[(size_t)g * HID + threadIdx.x] = acc;
    }
}

// ---------------- driver ----------------

extern "C" void kernel_launch(void* const* d_in, const int* in_sizes, int n_in,
                              void* d_out, int out_size, void* d_ws, size_t ws_size,
                              hipStream_t stream) {
    const float* x     = (const float*)d_in[0];
    const int*   ei    = (const int*)d_in[1];
    const int*   batch = (const int*)d_in[2];
    const float* bnfg  = (const float*)d_in[3];
    const float* bnfb  = (const float*)d_in[4];
    const float* Wfeat = (const float*)d_in[5];
    const float* bfeat = (const float*)d_in[6];
    const float* bng   = (const float*)d_in[7];
    const float* bnb   = (const float*)d_in[8];
    const float* Ws    = (const float*)d_in[9];
    const float* bs    = (const float*)d_in[10];
    float* out = (float*)d_out;

    const int N   = in_sizes[2];          // 50000
    const int E   = in_sizes[1] / 2;      // 800000
    const int FIN = in_sizes[0] / N;      // 128
    const int L   = in_sizes[9] / (HID * HID);  // 3
    const int G   = out_size / HID;       // 512

    // workspace layout (256B aligned slots); zeroed region first
    char* w = (char*)d_ws;
    auto alloc = [&](size_t bytes) { char* p = w; w += (bytes + 255) & ~(size_t)255; return p; };
    int*   deg    = (int*)alloc((size_t)N * 4);
    int*   cnt    = (int*)alloc((size_t)N * 4);
    int*   fill   = (int*)alloc((size_t)N * 4);
    float* stats  = (float*)alloc(1024 * 4);   // [0:256) layer0 (F=128), then 128 per GCN layer
    size_t zero_bytes = (size_t)(w - (char*)d_ws);
    int*   rowptr = (int*)alloc(((size_t)N + 1) * 4);
    int*   eidx   = (int*)alloc((size_t)E * 4);
    float* dis    = (float*)alloc((size_t)N * 4);
    float* Wf     = (float*)alloc((size_t)FIN * HID * 4);
    float* bf     = (float*)alloc(HID * 4);
    float* bufA   = (float*)alloc((size_t)N * HID * 4);
    float* bufB   = (float*)alloc((size_t)N * HID * 4);

    hipMemsetAsync(d_ws, 0, zero_bytes, stream);

    int gE = (E + 255) / 256;
    int gN = (N + 255) / 256;

    // graph structure
    k_count<<<gE, 256, 0, stream>>>(ei, E, deg, cnt);
    k_dis<<<gN, 256, 0, stream>>>(deg, dis, N);
    k_scan<<<1, 1024, 0, stream>>>(cnt, rowptr, N);
    k_fill<<<gE, 256, 0, stream>>>(ei, E, rowptr, fill, eidx);

    // feature layer: BN(x) -> linear -> relu  (BN folded into W)
    k_stats<128><<<256, 256, 0, stream>>>(x, N, stats);
    k_fold<128><<<HID, 128, 0, stream>>>(stats, bnfg, bnfb, Wfeat, bfeat, 1.f / (float)N, Wf, bf, 1);
    k_gemm<128, true, false><<<gN, 256, 0, stream>>>(x, Wf, bf, dis, bufA, N);

    // GCN layers
    for (int l = 0; l < L; ++l) {
        float* st = stats + 256 + 128 * l;
        k_stats<64><<<256, 256, 0, stream>>>(bufA, N, st);
        k_fold<64><<<HID, 64, 0, stream>>>(st, bng + (size_t)l * HID, bnb + (size_t)l * HID,
                                           Ws + (size_t)l * HID * HID, bf /*unused*/,
                                           1.f / (float)N, Wf, bf, 0);
        // s_j = dis_j * (BN(h)@W + b_fold)
        k_gemm<64, false, true><<<gN, 256, 0, stream>>>(bufA, Wf, bf, dis, bufB, N);
        // h_{l+1} = relu(dis_i*(s_i + sum in-edges s_j) + b_l)
        k_agg<<<(N + 3) / 4, 256, 0, stream>>>(bufB, rowptr, eidx, dis, bs + (size_t)l * HID, bufA, N);
    }

    // global_add_pool
    k_pool<<<G, 256, 0, stream>>>(bufA, batch, N, out);
}

// Round 2
// 461.716 us; speedup vs baseline: 1.2842x; 1.2842x over previous
//
#include <hip/hip_runtime.h>
#include <math.h>

#define HID 64
#define BN_EPS 1e-5f
#define NBMAX 256

typedef unsigned int uint;
typedef unsigned short ushort;

// ============ radix-bucketed CSR build (kills global-atomic histogram cost) ============

// Pass A: per-block LDS histograms of dst>>8 and src>>8; flush with ~NB atomics/block.
__global__ __launch_bounds__(256) void k_bucket_hist(const int* __restrict__ ei, int E, int NB,
                                                     int* __restrict__ bcnt_d, int* __restrict__ bcnt_s) {
    __shared__ int hd[NBMAX], hs[NBMAX];
    int t = threadIdx.x;
    if (t < NB) { hd[t] = 0; hs[t] = 0; }
    __syncthreads();
    for (int e = blockIdx.x * 256 + t; e < E; e += gridDim.x * 256) {
        int src = ei[e], dst = ei[E + e];
        atomicAdd(&hs[src >> 8], 1);
        atomicAdd(&hd[dst >> 8], 1);
    }
    __syncthreads();
    if (t < NB) {
        if (hd[t]) atomicAdd(&bcnt_d[t], hd[t]);
        if (hs[t]) atomicAdd(&bcnt_s[t], hs[t]);
    }
}

// Pass B: exclusive scan of the NB bucket counts (both arrays), init cursors.
__global__ __launch_bounds__(256) void k_bucket_scan(const int* __restrict__ bcnt_d, const int* __restrict__ bcnt_s,
                                                     int NB, int N, int E,
                                                     int* __restrict__ bbase_d, int* __restrict__ cursor_d,
                                                     int* __restrict__ bbase_s, int* __restrict__ cursor_s,
                                                     int* __restrict__ rowptr) {
    __shared__ int sh[256];
    int t = threadIdx.x;
    int v = (t < NB) ? bcnt_d[t] : 0;
    sh[t] = v; __syncthreads();
    for (int s = 1; s < 256; s <<= 1) { int u = (t >= s) ? sh[t - s] : 0; __syncthreads(); sh[t] += u; __syncthreads(); }
    int excl = sh[t] - v;
    if (t <= NB) bbase_d[t] = excl;
    if (t < NB) cursor_d[t] = excl;
    if (t == 0) rowptr[N] = E;   // robustness for N%256==0; k_build_csr also writes it when N%256!=0
    __syncthreads();
    v = (t < NB) ? bcnt_s[t] : 0;
    sh[t] = v; __syncthreads();
    for (int s = 1; s < 256; s <<= 1) { int u = (t >= s) ? sh[t - s] : 0; __syncthreads(); sh[t] += u; __syncthreads(); }
    excl = sh[t] - v;
    if (t <= NB) bbase_s[t] = excl;
    if (t < NB) cursor_s[t] = excl;
}

// Pass C: block-level reservation scatter. 1 global atomic per (block,bucket), LDS cursors per edge.
__global__ __launch_bounds__(256) void k_scatter(const int* __restrict__ ei, int E, int NB,
                                                 int* __restrict__ cursor_d, int* __restrict__ cursor_s,
                                                 unsigned long long* __restrict__ bedge, int* __restrict__ bsrc) {
    __shared__ int hd[NBMAX], hs[NBMAX], curd[NBMAX], curs[NBMAX];
    int t = threadIdx.x;
    int chunk = (E + gridDim.x - 1) / gridDim.x;
    int e0 = blockIdx.x * chunk;
    int e1 = min(e0 + chunk, E);
    if (t < NB) { hd[t] = 0; hs[t] = 0; }
    __syncthreads();
    for (int e = e0 + t; e < e1; e += 256) {
        int src = ei[e], dst = ei[E + e];
        atomicAdd(&hd[dst >> 8], 1);
        atomicAdd(&hs[src >> 8], 1);
    }
    __syncthreads();
    if (t < NB) {
        curd[t] = hd[t] ? atomicAdd(&cursor_d[t], hd[t]) : 0;
        curs[t] = hs[t] ? atomicAdd(&cursor_s[t], hs[t]) : 0;
    }
    __syncthreads();
    for (int e = e0 + t; e < e1; e += 256) {
        int src = ei[e], dst = ei[E + e];
        int pd = atomicAdd(&curd[dst >> 8], 1);
        bedge[pd] = ((unsigned long long)(uint)dst << 32) | (uint)src;
        int ps = atomicAdd(&curs[src >> 8], 1);
        bsrc[ps] = src;
    }
}

// Pass D: per dst-bucket: LDS 256-bin histogram + scan -> rowptr; LDS-cursor scatter -> eidx.
__global__ __launch_bounds__(256) void k_build_csr(const unsigned long long* __restrict__ bedge,
                                                   const int* __restrict__ bbase_d, int N,
                                                   int* __restrict__ rowptr, int* __restrict__ eidx) {
    __shared__ int h[256], off[256], cur[256];
    int t = threadIdx.x, b = blockIdx.x;
    int base = bbase_d[b], end = bbase_d[b + 1];
    h[t] = 0; __syncthreads();
    for (int p = base + t; p < end; p += 256)
        atomicAdd(&h[(int)(bedge[p] >> 32) & 255], 1);
    __syncthreads();
    off[t] = h[t]; __syncthreads();
    for (int s = 1; s < 256; s <<= 1) { int u = (t >= s) ? off[t - s] : 0; __syncthreads(); off[t] += u; __syncthreads(); }
    int excl = off[t] - h[t];
    int node = (b << 8) + t;
    if (node <= N) rowptr[node] = base + excl;
    cur[t] = excl; __syncthreads();
    for (int p = base + t; p < end; p += 256) {
        unsigned long long be = bedge[p];
        int bin = (int)(be >> 32) & 255;
        int pos = atomicAdd(&cur[bin], 1);
        eidx[base + pos] = (int)(uint)(be & 0xffffffffULL);
    }
}

// Pass D': per src-bucket: LDS histogram of outdeg -> dis = rsqrt(outdeg+1).
__global__ __launch_bounds__(256) void k_outdeg(const int* __restrict__ bsrc, const int* __restrict__ bbase_s,
                                                int N, float* __restrict__ dis) {
    __shared__ int h[256];
    int t = threadIdx.x, b = blockIdx.x;
    int base = bbase_s[b], end = bbase_s[b + 1];
    h[t] = 0; __syncthreads();
    for (int p = base + t; p < end; p += 256) atomicAdd(&h[bsrc[p] & 255], 1);
    __syncthreads();
    int node = (b << 8) + t;
    if (node < N) dis[node] = rsqrtf((float)(h[t] + 1));
}

// ============ BN stats ============

template <int F>
__global__ __launch_bounds__(256) void k_stats(const float* __restrict__ X, int n,
                                               float* __restrict__ stats) {
    const int RPB = 256 / F;
    int f = threadIdx.x & (F - 1);
    int rsub = threadIdx.x / F;
    float s = 0.f, q = 0.f;
    for (int r = blockIdx.x * RPB + rsub; r < n; r += gridDim.x * RPB) {
        float v = X[(size_t)r * F + f];
        s += v; q += v * v;
    }
    __shared__ float shs[256], shq[256];
    shs[threadIdx.x] = s; shq[threadIdx.x] = q;
    __syncthreads();
    if (threadIdx.x < F) {
        #pragma unroll
        for (int k = 1; k < RPB; k++) { s += shs[threadIdx.x + k * F]; q += shq[threadIdx.x + k * F]; }
        atomicAdd(&stats[f], s);
        atomicAdd(&stats[F + f], q);
    }
}

// ============ fold BN into linear ============

template <int K>
__global__ void k_fold(const float* __restrict__ stats, const float* __restrict__ gamma,
                       const float* __restrict__ beta, const float* __restrict__ W,
                       const float* __restrict__ bias, float n_inv,
                       float* __restrict__ Wout, float* __restrict__ bout, int has_bias) {
    int o = blockIdx.x;
    int f = threadIdx.x;
    float mu = stats[f] * n_inv;
    float var = stats[K + f] * n_inv - mu * mu;
    float a = gamma[f] * rsqrtf(var + BN_EPS);
    float w = W[(size_t)f * HID + o];
    Wout[(size_t)f * HID + o] = a * w;
    float contrib = (beta[f] - mu * a) * w;
    __shared__ float sh[K];
    sh[f] = contrib;
    __syncthreads();
    #pragma unroll
    for (int off = K / 2; off > 0; off >>= 1) {
        if (f < off) sh[f] += sh[f + off];
        __syncthreads();
    }
    if (f == 0) bout[o] = sh[0] + (has_bias ? bias[o] : 0.f);
}

// ============ GEMM ============

__device__ inline uint bf16pk(float a, float b) {
    uint ua = __builtin_bit_cast(uint, a);
    ua += 0x7fff + ((ua >> 16) & 1);
    uint ub = __builtin_bit_cast(uint, b);
    ub += 0x7fff + ((ub >> 16) & 1);
    return (ua >> 16) | (ub & 0xffff0000u);
}

// out[n,64] = X[n,K] @ W[K,64] + b.  DIS: scale row by dis[row] and store bf16. RELU: relu, store f32.
template <int K, bool RELU, bool DIS>
__global__ __launch_bounds__(256) void k_gemm(const float* __restrict__ X, const float* __restrict__ W,
                                              const float* __restrict__ bias, const float* __restrict__ dis,
                                              void* __restrict__ out, int n) {
    int row = blockIdx.x * 256 + threadIdx.x;
    if (row >= n) return;
    float4 acc[16];
    const float4* b4 = (const float4*)bias;
    #pragma unroll
    for (int c = 0; c < 16; c++) acc[c] = b4[c];
    const float* xrow = X + (size_t)row * K;
    #pragma unroll 1
    for (int kc = 0; kc < K; kc += 32) {
        float4 xr[8];
        const float4* xp = (const float4*)(xrow + kc);
        #pragma unroll
        for (int i = 0; i < 8; i++) xr[i] = xp[i];
        #pragma unroll
        for (int kk = 0; kk < 32; kk++) {
            float xv = ((const float*)xr)[kk];
            const float4* w4 = (const float4*)(W + (size_t)(kc + kk) * HID);
            #pragma unroll
            for (int c = 0; c < 16; c++) {
                float4 w = w4[c];
                acc[c].x = fmaf(xv, w.x, acc[c].x);
                acc[c].y = fmaf(xv, w.y, acc[c].y);
                acc[c].z = fmaf(xv, w.z, acc[c].z);
                acc[c].w = fmaf(xv, w.w, acc[c].w);
            }
        }
    }
    if constexpr (DIS) {
        float d = dis[row];
        uint4* o4 = (uint4*)((ushort*)out + (size_t)row * HID);
        #pragma unroll
        for (int c = 0; c < 8; c++) {
            float4 a = acc[2 * c], b = acc[2 * c + 1];
            uint4 pk;
            pk.x = bf16pk(a.x * d, a.y * d);
            pk.y = bf16pk(a.z * d, a.w * d);
            pk.z = bf16pk(b.x * d, b.y * d);
            pk.w = bf16pk(b.z * d, b.w * d);
            o4[c] = pk;
        }
    } else {
        float4* o4 = (float4*)((float*)out + (size_t)row * HID);
        #pragma unroll
        for (int c = 0; c < 16; c++) {
            float4 v = acc[c];
            if (RELU) { v.x = fmaxf(v.x, 0.f); v.y = fmaxf(v.y, 0.f); v.z = fmaxf(v.z, 0.f); v.w = fmaxf(v.w, 0.f); }
            o4[c] = v;
        }
    }
}

// ============ aggregation: out_i = relu(dis_i*(s_i + sum_{j->i} s_j) + b) ============
// s is bf16 [n,64]; 2 nodes per wave (32 lanes each, bf16x2 per lane), f32 accumulate.

__device__ inline float bfl(uint v) { return __builtin_bit_cast(float, v << 16); }
__device__ inline float bfh(uint v) { return __builtin_bit_cast(float, v & 0xffff0000u); }

__global__ __launch_bounds__(256) void k_agg(const ushort* __restrict__ s, const int* __restrict__ rowptr,
                                             const int* __restrict__ eidx, const float* __restrict__ dis,
                                             const float* __restrict__ bias, float* __restrict__ out, int n) {
    int wave = threadIdx.x >> 6;
    int lane = threadIdx.x & 63;
    int half = lane >> 5, li = lane & 31;
    int i = blockIdx.x * 8 + wave * 2 + half;
    if (i >= n) return;
    int f = li * 2;
    const uint* sp = (const uint*)s;  // row stride = 32 uints
    uint v = sp[(size_t)i * 32 + li];
    float ax = bfl(v), ay = bfh(v);   // self-loop term
    int q = rowptr[i], qe = rowptr[i + 1];
    for (; q + 4 <= qe; q += 4) {
        int j0 = eidx[q], j1 = eidx[q + 1], j2 = eidx[q + 2], j3 = eidx[q + 3];
        uint v0 = sp[(size_t)j0 * 32 + li];
        uint v1 = sp[(size_t)j1 * 32 + li];
        uint v2 = sp[(size_t)j2 * 32 + li];
        uint v3 = sp[(size_t)j3 * 32 + li];
        ax += (bfl(v0) + bfl(v1)) + (bfl(v2) + bfl(v3));
        ay += (bfh(v0) + bfh(v1)) + (bfh(v2) + bfh(v3));
    }
    for (; q < qe; ++q) {
        uint vv = sp[(size_t)eidx[q] * 32 + li];
        ax += bfl(vv); ay += bfh(vv);
    }
    float dd = dis[i];
    float2 r;
    r.x = fmaxf(fmaf(dd, ax, bias[f]), 0.f);
    r.y = fmaxf(fmaf(dd, ay, bias[f + 1]), 0.f);
    *(float2*)(out + (size_t)i * HID + f) = r;
}

// ============ global_add_pool ============

__global__ __launch_bounds__(256) void k_pool(const float* __restrict__ h, const int* __restrict__ batch,
                                              int n, float* __restrict__ out) {
    int g = blockIdx.x;
    int lo = 0, hi = n;
    while (lo < hi) { int mid = (lo + hi) >> 1; if (batch[mid] < g) lo = mid + 1; else hi = mid; }
    int start = lo;
    hi = n;
    while (lo < hi) { int mid = (lo + hi) >> 1; if (batch[mid] < g + 1) lo = mid + 1; else hi = mid; }
    int end = lo;
    int lane = threadIdx.x & 63;
    int rs = threadIdx.x >> 6;
    float acc = 0.f;
    for (int r = start + rs; r < end; r += 4) acc += h[(size_t)r * HID + lane];
    __shared__ float sh[256];
    sh[threadIdx.x] = acc;
    __syncthreads();
    if (threadIdx.x < 64) {
        acc = sh[threadIdx.x] + sh[64 + threadIdx.x] + sh[128 + threadIdx.x] + sh[192 + threadIdx.x];
        out[(size_t)g * HID + threadIdx.x] = acc;
    }
}

// ============ driver ============

extern "C" void kernel_launch(void* const* d_in, const int* in_sizes, int n_in,
                              void* d_out, int out_size, void* d_ws, size_t ws_size,
                              hipStream_t stream) {
    const float* x     = (const float*)d_in[0];
    const int*   ei    = (const int*)d_in[1];
    const int*   batch = (const int*)d_in[2];
    const float* bnfg  = (const float*)d_in[3];
    const float* bnfb  = (const float*)d_in[4];
    const float* Wfeat = (const float*)d_in[5];
    const float* bfeat = (const float*)d_in[6];
    const float* bng   = (const float*)d_in[7];
    const float* bnb   = (const float*)d_in[8];
    const float* Ws    = (const float*)d_in[9];
    const float* bs    = (const float*)d_in[10];
    float* out = (float*)d_out;

    const int N   = in_sizes[2];
    const int E   = in_sizes[1] / 2;
    const int FIN = in_sizes[0] / N;
    const int L   = in_sizes[9] / (HID * HID);
    const int G   = out_size / HID;
    const int NB  = (N + 255) >> 8;   // 196 radix buckets

    char* w = (char*)d_ws;
    auto alloc = [&](size_t bytes) { char* p = w; w += (bytes + 255) & ~(size_t)255; return p; };
    // zeroed region
    int*   bcnt_d = (int*)alloc(256 * 4);
    int*   bcnt_s = (int*)alloc(256 * 4);
    float* stats  = (float*)alloc(1024 * 4);
    size_t zero_bytes = (size_t)(w - (char*)d_ws);
    // non-zeroed
    int*   bbase_d  = (int*)alloc(257 * 4);
    int*   cursor_d = (int*)alloc(256 * 4);
    int*   bbase_s  = (int*)alloc(257 * 4);
    int*   cursor_s = (int*)alloc(256 * 4);
    int*   rowptr   = (int*)alloc(((size_t)N + 1) * 4);
    int*   eidx     = (int*)alloc((size_t)E * 4);
    float* dis      = (float*)alloc((size_t)N * 4);
    float* Wf       = (float*)alloc((size_t)FIN * HID * 4);
    float* bf       = (float*)alloc(HID * 4);
    float* bufA     = (float*)alloc((size_t)N * HID * 4);           // f32 h; aliases bedge
    ushort* bufB    = (ushort*)alloc((size_t)N * HID * 2);          // bf16 s; aliases bsrc
    // aliases (lifetimes disjoint in stream order):
    unsigned long long* bedge = (unsigned long long*)bufA;  // E*8 = 6.4MB <= N*HID*4 = 12.8MB
    int* bsrc = (int*)bufB;                                  // E*4 = 3.2MB <= N*HID*2 = 6.4MB

    hipMemsetAsync(d_ws, 0, zero_bytes, stream);

    int gN = (N + 255) / 256;

    // graph build (radix)
    k_bucket_hist<<<256, 256, 0, stream>>>(ei, E, NB, bcnt_d, bcnt_s);
    k_bucket_scan<<<1, 256, 0, stream>>>(bcnt_d, bcnt_s, NB, N, E,
                                         bbase_d, cursor_d, bbase_s, cursor_s, rowptr);
    k_scatter<<<256, 256, 0, stream>>>(ei, E, NB, cursor_d, cursor_s, bedge, bsrc);
    k_build_csr<<<NB, 256, 0, stream>>>(bedge, bbase_d, N, rowptr, eidx);
    k_outdeg<<<NB, 256, 0, stream>>>(bsrc, bbase_s, N, dis);

    // feature layer (BN folded into linear), bufA overwrites bedge (done)
    k_stats<128><<<256, 256, 0, stream>>>(x, N, stats);
    k_fold<128><<<HID, 128, 0, stream>>>(stats, bnfg, bnfb, Wfeat, bfeat, 1.f / (float)N, Wf, bf, 1);
    k_gemm<128, true, false><<<gN, 256, 0, stream>>>(x, Wf, bf, dis, bufA, N);

    // GCN layers
    for (int l = 0; l < L; ++l) {
        float* st = stats + 256 + 128 * l;
        k_stats<64><<<256, 256, 0, stream>>>(bufA, N, st);
        k_fold<64><<<HID, 64, 0, stream>>>(st, bng + (size_t)l * HID, bnb + (size_t)l * HID,
                                           Ws + (size_t)l * HID * HID, bf /*unused*/,
                                           1.f / (float)N, Wf, bf, 0);
        k_gemm<64, false, true><<<gN, 256, 0, stream>>>(bufA, Wf, bf, dis, (void*)bufB, N);
        k_agg<<<(N + 7) / 8, 256, 0, stream>>>(bufB, rowptr, eidx, dis, bs + (size_t)l * HID, bufA, N);
    }

    k_pool<<<G, 256, 0, stream>>>(bufA, batch, N, out);
}